// Round 1
// baseline (4680.113 us; speedup 1.0000x reference)
//
#include <hip/hip_runtime.h>
#include <math.h>

// Problem constants (SpikingSelfAttention)
constexpr int B_ = 8, S_ = 1024, E_ = 768, H_ = 12, D_ = 64, T_ = 10;
constexpr int N_ = B_ * S_;        // 8192 rows
constexpr int NE_ = N_ * E_;       // 6291456 elements per [N,E] buffer

constexpr int BM = 64, BN = 64, BK = 32;

__device__ __forceinline__ float sigm(float z) { return 1.0f / (1.0f + __expf(-z)); }

// ---------------- zero-fill (states must be zeroed every call) ----------------
__global__ __launch_bounds__(256) void zero_k(float4* __restrict__ p, int n4) {
    int i = blockIdx.x * 256 + threadIdx.x;
    if (i < n4) p[i] = make_float4(0.f, 0.f, 0.f, 0.f);
}

// ---------------- rate encode: inp = sigmoid(100*clip(x,0,1) - 10*t) ----------
__global__ __launch_bounds__(256) void encode_k(const float* __restrict__ x,
                                                float* __restrict__ inp, float t10) {
    int i = blockIdx.x * 256 + threadIdx.x;
    const float4* x4 = reinterpret_cast<const float4*>(x);
    float4* o4 = reinterpret_cast<float4*>(inp);
    float4 v = x4[i];
    float4 r;
    r.x = sigm(100.f * fminf(fmaxf(v.x, 0.f), 1.f) - t10);
    r.y = sigm(100.f * fminf(fmaxf(v.y, 0.f), 1.f) - t10);
    r.z = sigm(100.f * fminf(fmaxf(v.z, 0.f), 1.f) - t10);
    r.w = sigm(100.f * fminf(fmaxf(v.w, 0.f), 1.f) - t10);
    o4[i] = r;
}

// ---------------- fused QKV GEMM (NT) + LIF state update ----------------------
// C[n,m] = sum_k inp[n,k] * W[m,k] + bias[m]; then LIF on (v, C) accumulating spikes.
__global__ __launch_bounds__(256) void qkv_gemm_lif(
    const float* __restrict__ inp,
    const float* __restrict__ Wq, const float* __restrict__ Wk, const float* __restrict__ Wv,
    const float* __restrict__ biasq, const float* __restrict__ biask, const float* __restrict__ biasv,
    float* __restrict__ vq, float* __restrict__ vk, float* __restrict__ vv,
    float* __restrict__ Qa, float* __restrict__ Ka, float* __restrict__ Va) {
    const int z = blockIdx.z;
    const float* __restrict__ W    = (z == 0) ? Wq : (z == 1) ? Wk : Wv;
    const float* __restrict__ bias = (z == 0) ? biasq : (z == 1) ? biask : biasv;
    float* __restrict__ vst = (z == 0) ? vq : (z == 1) ? vk : vv;
    float* __restrict__ acc = (z == 0) ? Qa : (z == 1) ? Ka : Va;

    __shared__ float As[BK][BM + 4];   // transposed: As[k][m]
    __shared__ float Bs[BK][BN + 4];   // transposed: Bs[k][n]

    const int row0 = blockIdx.x * BM;
    const int col0 = blockIdx.y * BN;
    const int tid = threadIdx.x;
    const int tx = tid & 15;
    const int ty = tid >> 4;
    const int ldr = tid >> 3;          // 0..31
    const int ldc = (tid & 7) << 2;    // 0,4,...,28

    float accr[4][4] = {};

    for (int k0 = 0; k0 < E_; k0 += BK) {
#pragma unroll
        for (int rr = 0; rr < 2; ++rr) {
            const int r = ldr + rr * 32;
            float4 a4 = *reinterpret_cast<const float4*>(&inp[(row0 + r) * E_ + k0 + ldc]);
            float4 b4 = *reinterpret_cast<const float4*>(&W[(col0 + r) * E_ + k0 + ldc]);
            As[ldc + 0][r] = a4.x; As[ldc + 1][r] = a4.y;
            As[ldc + 2][r] = a4.z; As[ldc + 3][r] = a4.w;
            Bs[ldc + 0][r] = b4.x; Bs[ldc + 1][r] = b4.y;
            Bs[ldc + 2][r] = b4.z; Bs[ldc + 3][r] = b4.w;
        }
        __syncthreads();
#pragma unroll
        for (int kk = 0; kk < BK; ++kk) {
            float4 a4 = *reinterpret_cast<const float4*>(&As[kk][ty << 2]);
            float4 b4 = *reinterpret_cast<const float4*>(&Bs[kk][tx << 2]);
            float av[4] = {a4.x, a4.y, a4.z, a4.w};
            float bw[4] = {b4.x, b4.y, b4.z, b4.w};
#pragma unroll
            for (int i = 0; i < 4; ++i)
#pragma unroll
                for (int j = 0; j < 4; ++j)
                    accr[i][j] = fmaf(av[i], bw[j], accr[i][j]);
        }
        __syncthreads();
    }

#pragma unroll
    for (int i = 0; i < 4; ++i) {
        const int n = row0 + (ty << 2) + i;
#pragma unroll
        for (int j = 0; j < 4; ++j) {
            const int m = col0 + (tx << 2) + j;
            const int idx = n * E_ + m;
            float I = accr[i][j] + bias[m];
            float v = (vst[idx] + I) * 0.5f;            // v += (I - v)/2
            float spk = sigm(10.f * (v - 1.f));
            vst[idx] = v * (1.f - spk);
            acc[idx] += spk;
        }
    }
}

// ---------------- output projection GEMM + fresh-state LIF spike --------------
__global__ __launch_bounds__(256) void out_gemm_spk(
    const float* __restrict__ Ain, const float* __restrict__ W,
    const float* __restrict__ bias, float* __restrict__ out) {
    __shared__ float As[BK][BM + 4];
    __shared__ float Bs[BK][BN + 4];

    const int row0 = blockIdx.x * BM;
    const int col0 = blockIdx.y * BN;
    const int tid = threadIdx.x;
    const int tx = tid & 15;
    const int ty = tid >> 4;
    const int ldr = tid >> 3;
    const int ldc = (tid & 7) << 2;

    float accr[4][4] = {};

    for (int k0 = 0; k0 < E_; k0 += BK) {
#pragma unroll
        for (int rr = 0; rr < 2; ++rr) {
            const int r = ldr + rr * 32;
            float4 a4 = *reinterpret_cast<const float4*>(&Ain[(row0 + r) * E_ + k0 + ldc]);
            float4 b4 = *reinterpret_cast<const float4*>(&W[(col0 + r) * E_ + k0 + ldc]);
            As[ldc + 0][r] = a4.x; As[ldc + 1][r] = a4.y;
            As[ldc + 2][r] = a4.z; As[ldc + 3][r] = a4.w;
            Bs[ldc + 0][r] = b4.x; Bs[ldc + 1][r] = b4.y;
            Bs[ldc + 2][r] = b4.z; Bs[ldc + 3][r] = b4.w;
        }
        __syncthreads();
#pragma unroll
        for (int kk = 0; kk < BK; ++kk) {
            float4 a4 = *reinterpret_cast<const float4*>(&As[kk][ty << 2]);
            float4 b4 = *reinterpret_cast<const float4*>(&Bs[kk][tx << 2]);
            float av[4] = {a4.x, a4.y, a4.z, a4.w};
            float bw[4] = {b4.x, b4.y, b4.z, b4.w};
#pragma unroll
            for (int i = 0; i < 4; ++i)
#pragma unroll
                for (int j = 0; j < 4; ++j)
                    accr[i][j] = fmaf(av[i], bw[j], accr[i][j]);
        }
        __syncthreads();
    }

#pragma unroll
    for (int i = 0; i < 4; ++i) {
        const int n = row0 + (ty << 2) + i;
#pragma unroll
        for (int j = 0; j < 4; ++j) {
            const int m = col0 + (tx << 2) + j;
            float I = accr[i][j] + bias[m];
            // lif_step(0, I): v = I/2; spk = sigmoid(10*(v-1)) = sigmoid(5I - 10)
            out[n * E_ + m] = sigm(5.f * I - 10.f);
        }
    }
}

// ---------------- flash-style attention per (b, h, q-tile of 64) --------------
__global__ __launch_bounds__(256) void attn_k(
    const float* __restrict__ Q, const float* __restrict__ K,
    const float* __restrict__ V, float* __restrict__ O) {
    const int q0 = blockIdx.x * 64;
    const int h = blockIdx.y;
    const int b = blockIdx.z;

    __shared__ float Qt[D_][64 + 4];   // Qt[d][row]
    __shared__ float Kt[D_][64 + 4];   // Kt[d][col]
    __shared__ float Vs[64][D_ + 4];   // Vs[key][d]
    __shared__ float Ps[64][64 + 4];   // score/prob tile
    __shared__ float mrow[64], lrow[64], arow[64];

    const int tid = threadIdx.x;
    const int tx = tid & 15, ty = tid >> 4;
    const int lr = tid >> 4;           // 0..15
    const int lc = (tid & 15) << 2;    // 0..60

#pragma unroll
    for (int rr = 0; rr < 4; ++rr) {
        int r = lr + rr * 16;
        float4 q4 = *reinterpret_cast<const float4*>(&Q[((b * S_) + q0 + r) * E_ + h * D_ + lc]);
        Qt[lc + 0][r] = q4.x; Qt[lc + 1][r] = q4.y;
        Qt[lc + 2][r] = q4.z; Qt[lc + 3][r] = q4.w;
    }
    if (tid < 64) { mrow[tid] = -INFINITY; lrow[tid] = 0.f; }

    float o[4][4] = {};

    for (int kt = 0; kt < S_ / 64; ++kt) {
        __syncthreads();   // previous PV done before overwriting Kt/Vs
        const int k0 = kt * 64;
#pragma unroll
        for (int rr = 0; rr < 4; ++rr) {
            int r = lr + rr * 16;
            float4 k4 = *reinterpret_cast<const float4*>(&K[((b * S_) + k0 + r) * E_ + h * D_ + lc]);
            Kt[lc + 0][r] = k4.x; Kt[lc + 1][r] = k4.y;
            Kt[lc + 2][r] = k4.z; Kt[lc + 3][r] = k4.w;
            float4 v4 = *reinterpret_cast<const float4*>(&V[((b * S_) + k0 + r) * E_ + h * D_ + lc]);
            *reinterpret_cast<float4*>(&Vs[r][lc]) = v4;
        }
        __syncthreads();

        // scores S = (Q K^T) / 8
        float s[4][4] = {};
#pragma unroll 8
        for (int d = 0; d < D_; ++d) {
            float4 a4 = *reinterpret_cast<const float4*>(&Qt[d][ty << 2]);
            float4 b4 = *reinterpret_cast<const float4*>(&Kt[d][tx << 2]);
            float av[4] = {a4.x, a4.y, a4.z, a4.w};
            float bw[4] = {b4.x, b4.y, b4.z, b4.w};
#pragma unroll
            for (int i = 0; i < 4; ++i)
#pragma unroll
                for (int j = 0; j < 4; ++j)
                    s[i][j] = fmaf(av[i], bw[j], s[i][j]);
        }
#pragma unroll
        for (int i = 0; i < 4; ++i)
#pragma unroll
            for (int j = 0; j < 4; ++j)
                Ps[(ty << 2) + i][(tx << 2) + j] = s[i][j] * 0.125f;
        __syncthreads();

        // online softmax row pass (one thread per row)
        if (tid < 64) {
            const int r = tid;
            float mold = mrow[r];
            float tmax = -INFINITY;
            for (int c = 0; c < 64; ++c) tmax = fmaxf(tmax, Ps[r][c]);
            float mnew = fmaxf(mold, tmax);
            float a = __expf(mold - mnew);
            float ls = 0.f;
            for (int c = 0; c < 64; ++c) {
                float p = __expf(Ps[r][c] - mnew);
                Ps[r][c] = p;
                ls += p;
            }
            lrow[r] = lrow[r] * a + ls;
            mrow[r] = mnew;
            arow[r] = a;
        }
        __syncthreads();

        // rescale accumulators + O += P V
        float al[4];
#pragma unroll
        for (int i = 0; i < 4; ++i) al[i] = arow[(ty << 2) + i];
#pragma unroll
        for (int i = 0; i < 4; ++i)
#pragma unroll
            for (int j = 0; j < 4; ++j) o[i][j] *= al[i];
#pragma unroll 8
        for (int kk = 0; kk < 64; ++kk) {
            float4 v4 = *reinterpret_cast<const float4*>(&Vs[kk][tx << 2]);
            float vw[4] = {v4.x, v4.y, v4.z, v4.w};
            float p[4];
#pragma unroll
            for (int i = 0; i < 4; ++i) p[i] = Ps[(ty << 2) + i][kk];
#pragma unroll
            for (int i = 0; i < 4; ++i)
#pragma unroll
                for (int j = 0; j < 4; ++j)
                    o[i][j] = fmaf(p[i], vw[j], o[i][j]);
        }
    }
    __syncthreads();

    float linv[4];
#pragma unroll
    for (int i = 0; i < 4; ++i) linv[i] = 1.f / lrow[(ty << 2) + i];
#pragma unroll
    for (int i = 0; i < 4; ++i)
#pragma unroll
        for (int j = 0; j < 4; ++j)
            O[((b * S_) + q0 + (ty << 2) + i) * E_ + h * D_ + (tx << 2) + j] =
                o[i][j] * linv[i];
}

// -----------------------------------------------------------------------------
extern "C" void kernel_launch(void* const* d_in, const int* in_sizes, int n_in,
                              void* d_out, int out_size, void* d_ws, size_t ws_size,
                              hipStream_t stream) {
    const float* x  = (const float*)d_in[0];
    const float* Wq = (const float*)d_in[1];
    const float* bq = (const float*)d_in[2];
    const float* Wk = (const float*)d_in[3];
    const float* bk = (const float*)d_in[4];
    const float* Wv = (const float*)d_in[5];
    const float* bv = (const float*)d_in[6];
    const float* Wo = (const float*)d_in[7];
    const float* bo = (const float*)d_in[8];
    float* out = (float*)d_out;

    float* fw = (float*)d_ws;
    float* vq = fw;                 // [N,E] membrane states
    float* vk = vq + NE_;
    float* vv = vk + NE_;
    float* Qa = vv + NE_;           // [N,E] spike accumulators
    float* Ka = Qa + NE_;
    float* Va = Ka + NE_;
    float* inp = Va + NE_;          // [N,E] encoded spikes at step t
    float* att = inp;               // reuse after time loop

    // zero the 6 state/accumulator buffers (harness doesn't re-poison between replays)
    {
        int n4 = 6 * NE_ / 4;
        zero_k<<<dim3((n4 + 255) / 256), 256, 0, stream>>>((float4*)d_ws, n4);
    }

    dim3 gEnc(NE_ / 4 / 256);                 // 6144 blocks
    dim3 gQKV(N_ / BM, E_ / BN, 3);           // 128 x 12 x 3
    for (int t = 0; t < T_; ++t) {
        encode_k<<<gEnc, 256, 0, stream>>>(x, inp, 10.f * (float)t);
        qkv_gemm_lif<<<gQKV, 256, 0, stream>>>(inp, Wq, Wk, Wv, bq, bk, bv,
                                               vq, vk, vv, Qa, Ka, Va);
    }
    attn_k<<<dim3(S_ / 64, H_, B_), 256, 0, stream>>>(Qa, Ka, Va, att);
    out_gemm_spk<<<dim3(N_ / BM, E_ / BN), 256, 0, stream>>>(att, Wo, bo, out);
}

// Round 2
// 800.874 us; speedup vs baseline: 5.8438x; 5.8438x over previous
//
#include <hip/hip_runtime.h>
#include <math.h>

// SpikingSelfAttention: B=8 S=1024 E=768 H=12 D=64 T=10
constexpr int B_ = 8, S_ = 1024, E_ = 768, H_ = 12, D_ = 64, T_ = 10;
constexpr int N_ = B_ * S_;        // 8192
constexpr int NE_ = N_ * E_;       // 6291456
constexpr int WE_ = E_ * E_;       // 589824

typedef __attribute__((ext_vector_type(8))) short bf16x8;
typedef __attribute__((ext_vector_type(4))) float f32x4;

#define MFMA16(a,b,c) __builtin_amdgcn_mfma_f32_16x16x32_bf16(a,b,c,0,0,0)

__device__ __forceinline__ float sigm(float z){ return 1.f/(1.f+__expf(-z)); }
__device__ __forceinline__ unsigned short f2bf(float f){
    unsigned int u = __float_as_uint(f);
    u += 0x7FFFu + ((u>>16)&1u);           // RN-even
    return (unsigned short)(u>>16);
}
__device__ __forceinline__ float bf2f(unsigned short h){
    return __uint_as_float(((unsigned int)h)<<16);
}
__device__ __forceinline__ void gl16(const void* g, void* l){
    __builtin_amdgcn_global_load_lds((const __attribute__((address_space(1))) unsigned int*)g,
                                     (__attribute__((address_space(3))) unsigned int*)l, 16, 0, 0);
}

// ---------------------------------------------------------------------------
// encode: enc[t][n][e] = bf16(sigmoid(100*clip(x,0,1) - 10t)), 8 elems/thread
__global__ __launch_bounds__(256) void encode_k(const float* __restrict__ x,
                                                unsigned short* __restrict__ enc){
    const int i = blockIdx.x*256 + threadIdx.x;
    const float4 a = ((const float4*)x)[2*i];
    const float4 b = ((const float4*)x)[2*i+1];
    float p[8] = {a.x,a.y,a.z,a.w,b.x,b.y,b.z,b.w};
#pragma unroll
    for (int e=0;e<8;++e) p[e] = 100.f*fminf(fmaxf(p[e],0.f),1.f);
#pragma unroll
    for (int t=0;t<T_;++t){
        unsigned int w[4];
#pragma unroll
        for (int e=0;e<4;++e){
            unsigned short u0 = f2bf(sigm(p[2*e]   - 10.f*(float)t));
            unsigned short u1 = f2bf(sigm(p[2*e+1] - 10.f*(float)t));
            w[e] = (unsigned int)u0 | ((unsigned int)u1<<16);
        }
        ((uint4*)(enc + (long)t*NE_))[i] = make_uint4(w[0],w[1],w[2],w[3]);
    }
}

// ---------------------------------------------------------------------------
// split weights into hi/lo bf16: whi[z], wlo[z], z in {q,k,v,o}
__global__ __launch_bounds__(256) void wsplit_k(const float* __restrict__ Wq, const float* __restrict__ Wk,
        const float* __restrict__ Wv, const float* __restrict__ Wo,
        unsigned short* __restrict__ whi, unsigned short* __restrict__ wlo){
    int gi = blockIdx.x*256 + threadIdx.x;
    int z = gi / (WE_/8);
    int r = gi % (WE_/8);
    const float* W = z==0?Wq : z==1?Wk : z==2?Wv : Wo;
    const float4 a = ((const float4*)W)[2*r];
    const float4 b = ((const float4*)W)[2*r+1];
    float f[8]={a.x,a.y,a.z,a.w,b.x,b.y,b.z,b.w};
    unsigned int h[4], l[4];
#pragma unroll
    for (int e=0;e<4;++e){
        unsigned short h0=f2bf(f[2*e]),   l0=f2bf(f[2*e]  -bf2f(h0));
        unsigned short h1=f2bf(f[2*e+1]), l1=f2bf(f[2*e+1]-bf2f(h1));
        h[e] = (unsigned)h0 | ((unsigned)h1<<16);
        l[e] = (unsigned)l0 | ((unsigned)l1<<16);
    }
    ((uint4*)(whi + (long)z*WE_))[r] = make_uint4(h[0],h[1],h[2],h[3]);
    ((uint4*)(wlo + (long)z*WE_))[r] = make_uint4(l[0],l[1],l[2],l[3]);
}

// ---------------------------------------------------------------------------
// fused QKV GEMM (MFMA, W hi/lo split) + in-register LIF over 10 timesteps.
// tile 128x64, 4 waves (2x2), BK=64, single-buffered LDS via global_load_lds.
__global__ __launch_bounds__(256,2) void qkv_k(const unsigned short* __restrict__ enc,
        const unsigned short* __restrict__ whi, const unsigned short* __restrict__ wlo,
        const float* __restrict__ bq, const float* __restrict__ bk, const float* __restrict__ bv,
        float* __restrict__ Qf, float* __restrict__ Kf, float* __restrict__ Vf){
    const int z = blockIdx.z;
    const unsigned short* Wh = whi + (long)z*WE_;
    const unsigned short* Wl = wlo + (long)z*WE_;
    const float* bias = z==0?bq : z==1?bk : bv;
    float* Out = z==0?Qf : z==1?Kf : Vf;
    const int row0 = blockIdx.x*128, col0 = blockIdx.y*64;

    __shared__ unsigned short Ab[128*64];   // 16KB, rows 128B, XOR-swizzled chunks
    __shared__ unsigned short Bh[64*64];    // 8KB
    __shared__ unsigned short Bl[64*64];    // 8KB

    const int tid = threadIdx.x, lane = tid&63, wid = tid>>6;
    const int l15 = lane&15, l4 = lane>>4, l7 = lane&7;
    const int wr = wid>>1, wc = wid&1;

    // staging source offsets (element units); LDS dest linear, source pre-inverse-swizzled
    int aSrc[4], bSrc[2];
#pragma unroll
    for (int s=0;s<4;++s){
        int idx = (wid + s*4)*64 + lane;      // [0,1024)
        int row = idx>>3, ch = idx&7;
        aSrc[s] = (row0+row)*E_ + ((ch ^ (row&7))<<3);
    }
#pragma unroll
    for (int s=0;s<2;++s){
        int idx = (wid + s*4)*64 + lane;      // [0,512)
        int row = idx>>3, ch = idx&7;
        bSrc[s] = (col0+row)*E_ + ((ch ^ (row&7))<<3);
    }

    const int aBase = (wr*64 + l15)*128;
    const int bBase = (wc*32 + l15)*128;
    const int sw[2] = { ((l4^l7)<<4), ((((4+l4))^l7)<<4) };

    f32x4 acc[4][2];
    float vm[4][2][4] = {};     // membrane potential (registers across t)
    float qa[4][2][4] = {};     // spike accumulator
    float bn[2];
#pragma unroll
    for (int n=0;n<2;++n) bn[n] = bias[col0 + wc*32 + n*16 + l15];
    const f32x4 zero4 = {0.f,0.f,0.f,0.f};

    for (int t=0;t<T_;++t){
        const long tb = (long)t*NE_;
#pragma unroll
        for (int m=0;m<4;++m)
#pragma unroll
            for (int n=0;n<2;++n) acc[m][n] = zero4;
        for (int kt=0;kt<12;++kt){
            const int k0 = kt*64;
            __syncthreads();
#pragma unroll
            for (int s=0;s<4;++s)
                gl16(enc + tb + aSrc[s] + k0, &Ab[(wid+s*4)*512]);
#pragma unroll
            for (int s=0;s<2;++s){
                gl16(Wh + bSrc[s] + k0, &Bh[(wid+s*4)*512]);
                gl16(Wl + bSrc[s] + k0, &Bl[(wid+s*4)*512]);
            }
            __syncthreads();
#pragma unroll
            for (int kk=0;kk<2;++kk){
                bf16x8 af[4], fbh[2], fbl[2];
#pragma unroll
                for (int m=0;m<4;++m)
                    af[m] = *(const bf16x8*)((const char*)Ab + aBase + m*2048 + sw[kk]);
#pragma unroll
                for (int n=0;n<2;++n){
                    fbh[n] = *(const bf16x8*)((const char*)Bh + bBase + n*2048 + sw[kk]);
                    fbl[n] = *(const bf16x8*)((const char*)Bl + bBase + n*2048 + sw[kk]);
                }
#pragma unroll
                for (int m=0;m<4;++m)
#pragma unroll
                    for (int n=0;n<2;++n){
                        acc[m][n] = MFMA16(af[m], fbh[n], acc[m][n]);
                        acc[m][n] = MFMA16(af[m], fbl[n], acc[m][n]);
                    }
            }
        }
        // LIF update, registers only (no barrier needed)
#pragma unroll
        for (int m=0;m<4;++m)
#pragma unroll
            for (int n=0;n<2;++n)
#pragma unroll
                for (int j=0;j<4;++j){
                    float I = acc[m][n][j] + bn[n];
                    float v = (vm[m][n][j] + I)*0.5f;
                    float s = sigm(10.f*v - 10.f);
                    vm[m][n][j] = v*(1.f - s);
                    qa[m][n][j] += s;
                }
    }
#pragma unroll
    for (int m=0;m<4;++m)
#pragma unroll
        for (int n=0;n<2;++n)
#pragma unroll
            for (int j=0;j<4;++j){
                int row = row0 + wr*64 + m*16 + l4*4 + j;
                int col = col0 + wc*32 + n*16 + l15;
                Out[(long)row*E_ + col] = qa[m][n][j];
            }
}

// ---------------------------------------------------------------------------
// flash attention, hi/lo-split bf16 MFMA. Per block: 64 q-rows, one (b,h).
// S^T = mfma(K, Q^T-frags); softmax per-lane q; O^T = mfma(V^T, P^T).
__global__ __launch_bounds__(256,2) void attn_k2(const float* __restrict__ Qf, const float* __restrict__ Kf,
        const float* __restrict__ Vf, unsigned short* __restrict__ atth, unsigned short* __restrict__ attl){
    const int q0 = blockIdx.x*64;
    const int h  = blockIdx.y;
    const int b  = blockIdx.z;
    const long base = ((long)b*S_)*E_ + h*64;

    __shared__ char smem[65536];
    unsigned short* Qh = (unsigned short*)(smem);
    unsigned short* Ql = (unsigned short*)(smem + 8192);
    unsigned short* Kh = (unsigned short*)(smem + 16384);
    unsigned short* Kl = (unsigned short*)(smem + 24576);
    unsigned short* Vh = (unsigned short*)(smem + 32768);  // [d][key] transposed
    unsigned short* Vl = (unsigned short*)(smem + 40960);
    unsigned short* Ph = (unsigned short*)(smem + 49152);  // [q][key]
    unsigned short* Pl = (unsigned short*)(smem + 57344);
    float* OT = (float*)(smem + 16384);                    // [64][68] reuse K/V region

    const int tid = threadIdx.x, lane = tid&63, wid = tid>>6;
    const int l15 = lane&15, l4 = lane>>4, l7 = lane&7;
    const int qrow = wid*16 + l15;

    // stage Q split (once)
    {
        int q = tid>>2, c0 = (tid&3)*2;
        const float* src = Qf + base + (long)(q0+q)*E_ + (tid&3)*16;
        float4 f0=((const float4*)src)[0], f1=((const float4*)src)[1];
        float4 f2=((const float4*)src)[2], f3=((const float4*)src)[3];
        float f[16]={f0.x,f0.y,f0.z,f0.w,f1.x,f1.y,f1.z,f1.w,f2.x,f2.y,f2.z,f2.w,f3.x,f3.y,f3.z,f3.w};
        bf16x8 vh[2], vl[2];
#pragma unroll
        for (int g=0;g<2;++g)
#pragma unroll
            for (int e=0;e<8;++e){
                unsigned short hh = f2bf(f[g*8+e]);
                vh[g][e] = (short)hh;
                vl[g][e] = (short)f2bf(f[g*8+e]-bf2f(hh));
            }
        int by0 = q*128 + (((c0  ) ^ (q&7))<<4);
        int by1 = q*128 + (((c0+1) ^ (q&7))<<4);
        *(bf16x8*)((char*)Qh + by0) = vh[0];
        *(bf16x8*)((char*)Qh + by1) = vh[1];
        *(bf16x8*)((char*)Ql + by0) = vl[0];
        *(bf16x8*)((char*)Ql + by1) = vl[1];
    }
    __syncthreads();
    bf16x8 qfh[2], qfl[2];
#pragma unroll
    for (int kk=0;kk<2;++kk){
        int off = qrow*128 + ((((kk<<2)+l4) ^ l7)<<4);
        qfh[kk] = *(const bf16x8*)((const char*)Qh + off);
        qfl[kk] = *(const bf16x8*)((const char*)Ql + off);
    }

    float mrun = -1e30f, lrun = 0.f;
    f32x4 ot[4];
    const f32x4 zero4 = {0.f,0.f,0.f,0.f};
#pragma unroll
    for (int m=0;m<4;++m) ot[m] = zero4;

    for (int kt=0;kt<16;++kt){
        const int k0 = kt*64;
        __syncthreads();
        // stage K split
        {
            int key = tid>>2, c0 = (tid&3)*2;
            const float* src = Kf + base + (long)(k0+key)*E_ + (tid&3)*16;
            float4 f0=((const float4*)src)[0], f1=((const float4*)src)[1];
            float4 f2=((const float4*)src)[2], f3=((const float4*)src)[3];
            float f[16]={f0.x,f0.y,f0.z,f0.w,f1.x,f1.y,f1.z,f1.w,f2.x,f2.y,f2.z,f2.w,f3.x,f3.y,f3.z,f3.w};
            bf16x8 vh[2], vl[2];
#pragma unroll
            for (int g=0;g<2;++g)
#pragma unroll
                for (int e=0;e<8;++e){
                    unsigned short hh = f2bf(f[g*8+e]);
                    vh[g][e] = (short)hh;
                    vl[g][e] = (short)f2bf(f[g*8+e]-bf2f(hh));
                }
            int by0 = key*128 + (((c0  ) ^ (key&7))<<4);
            int by1 = key*128 + (((c0+1) ^ (key&7))<<4);
            *(bf16x8*)((char*)Kh + by0) = vh[0];
            *(bf16x8*)((char*)Kh + by1) = vh[1];
            *(bf16x8*)((char*)Kl + by0) = vl[0];
            *(bf16x8*)((char*)Kl + by1) = vl[1];
        }
        // stage V transposed + split, packed b32 writes
#pragma unroll
        for (int rr=0;rr<2;++rr){
            int dq = (tid>>5) + rr*8;      // d-quad [0,16)
            int kp = tid&31;               // key pair
            const float* s0 = Vf + base + (long)(k0 + 2*kp)*E_ + dq*4;
            float4 va = *(const float4*)s0;
            float4 vb = *(const float4*)(s0 + E_);
            float fa[4]={va.x,va.y,va.z,va.w}, fb[4]={vb.x,vb.y,vb.z,vb.w};
#pragma unroll
            for (int dd=0;dd<4;++dd){
                int d = dq*4+dd;
                unsigned short ha=f2bf(fa[dd]), hb=f2bf(fb[dd]);
                unsigned short la=f2bf(fa[dd]-bf2f(ha)), lb=f2bf(fb[dd]-bf2f(hb));
                int byte = d*128 + ((kp<<2) ^ ((d&7)<<4));
                *(unsigned int*)((char*)Vh + byte) = (unsigned)ha | ((unsigned)hb<<16);
                *(unsigned int*)((char*)Vl + byte) = (unsigned)la | ((unsigned)lb<<16);
            }
        }
        __syncthreads();
        // S^T = K * Q^T  (3 hi/lo products)
        f32x4 st[4];
#pragma unroll
        for (int m=0;m<4;++m) st[m] = zero4;
#pragma unroll
        for (int kk=0;kk<2;++kk){
            int swo = ((((kk<<2)+l4) ^ l7)<<4);
            bf16x8 kh[4], kl2[4];
#pragma unroll
            for (int m=0;m<4;++m){
                int off = (m*16+l15)*128 + swo;
                kh[m]  = *(const bf16x8*)((const char*)Kh + off);
                kl2[m] = *(const bf16x8*)((const char*)Kl + off);
            }
#pragma unroll
            for (int m=0;m<4;++m){
                st[m] = MFMA16(kh[m],  qfh[kk], st[m]);
                st[m] = MFMA16(kh[m],  qfl[kk], st[m]);
                st[m] = MFMA16(kl2[m], qfh[kk], st[m]);
            }
        }
        // online softmax (lane's q = qrow; 4 lanes share a q via xor16/32)
        float pmax = -1e30f;
#pragma unroll
        for (int m=0;m<4;++m)
#pragma unroll
            for (int j=0;j<4;++j){ st[m][j] *= 0.125f; pmax = fmaxf(pmax, st[m][j]); }
        pmax = fmaxf(pmax, __shfl_xor(pmax,16));
        pmax = fmaxf(pmax, __shfl_xor(pmax,32));
        float mnew = fmaxf(mrun, pmax);
        float alpha = __expf(mrun - mnew);
        float p[16]; float psum = 0.f;
#pragma unroll
        for (int m=0;m<4;++m)
#pragma unroll
            for (int j=0;j<4;++j){ float e = __expf(st[m][j]-mnew); p[m*4+j]=e; psum+=e; }
        psum += __shfl_xor(psum,16);
        psum += __shfl_xor(psum,32);
        lrun = lrun*alpha + psum;
        mrun = mnew;
#pragma unroll
        for (int m=0;m<4;++m)
#pragma unroll
            for (int j=0;j<4;++j) ot[m][j] *= alpha;
        // write P^T split (wave-private rows, packed pairs)
#pragma unroll
        for (int m=0;m<4;++m)
#pragma unroll
            for (int jp=0;jp<2;++jp){
                float fx = p[m*4+jp*2], fy = p[m*4+jp*2+1];
                unsigned short hx=f2bf(fx), hy=f2bf(fy);
                unsigned short lx=f2bf(fx-bf2f(hx)), ly=f2bf(fy-bf2f(hy));
                int key = m*16 + l4*4 + jp*2;
                int byte = qrow*128 + ((key<<1) ^ (l7<<4));
                *(unsigned int*)((char*)Ph + byte) = (unsigned)hx | ((unsigned)hy<<16);
                *(unsigned int*)((char*)Pl + byte) = (unsigned)lx | ((unsigned)ly<<16);
            }
        // O^T += V^T * P^T (3 hi/lo products)
#pragma unroll
        for (int kk=0;kk<2;++kk){
            int swo = ((((kk<<2)+l4) ^ l7)<<4);
            bf16x8 pfh = *(const bf16x8*)((const char*)Ph + qrow*128 + swo);
            bf16x8 pfl = *(const bf16x8*)((const char*)Pl + qrow*128 + swo);
#pragma unroll
            for (int m=0;m<4;++m){
                int off = (m*16+l15)*128 + swo;
                bf16x8 vvh = *(const bf16x8*)((const char*)Vh + off);
                bf16x8 vvl = *(const bf16x8*)((const char*)Vl + off);
                ot[m] = MFMA16(vvh, pfh, ot[m]);
                ot[m] = MFMA16(vvh, pfl, ot[m]);
                ot[m] = MFMA16(vvl, pfh, ot[m]);
            }
        }
    }
    __syncthreads();
    // normalize + transpose via LDS, write att split bf16
    float inv = 1.f/lrun;
#pragma unroll
    for (int m=0;m<4;++m)
#pragma unroll
        for (int j=0;j<4;++j){
            int d = m*16 + l4*4 + j;
            OT[qrow*68 + d] = ot[m][j]*inv;
        }
    __syncthreads();
    {
        int q = tid>>2, d0 = (tid&3)*16;
        const float* rp = OT + q*68 + d0;
        float4 f0=((const float4*)rp)[0], f1=((const float4*)rp)[1];
        float4 f2=((const float4*)rp)[2], f3=((const float4*)rp)[3];
        float f[16]={f0.x,f0.y,f0.z,f0.w,f1.x,f1.y,f1.z,f1.w,f2.x,f2.y,f2.z,f2.w,f3.x,f3.y,f3.z,f3.w};
        bf16x8 vh[2], vl[2];
#pragma unroll
        for (int g=0;g<2;++g)
#pragma unroll
            for (int e=0;e<8;++e){
                unsigned short hh = f2bf(f[g*8+e]);
                vh[g][e] = (short)hh;
                vl[g][e] = (short)f2bf(f[g*8+e]-bf2f(hh));
            }
        long o = base + (long)(q0+q)*E_ + d0;
        *(bf16x8*)(atth + o)     = vh[0];
        *(bf16x8*)(atth + o + 8) = vh[1];
        *(bf16x8*)(attl + o)     = vl[0];
        *(bf16x8*)(attl + o + 8) = vl[1];
    }
}

// ---------------------------------------------------------------------------
// output projection GEMM (att hi/lo x Wo hi/lo, 3 products) + fresh-state spike
__global__ __launch_bounds__(256,2) void out_k(const unsigned short* __restrict__ Ah_g,
        const unsigned short* __restrict__ Al_g,
        const unsigned short* __restrict__ Wh, const unsigned short* __restrict__ Wl,
        const float* __restrict__ bias, float* __restrict__ out){
    const int row0 = blockIdx.x*128, col0 = blockIdx.y*64;
    __shared__ unsigned short Ah[128*64], Al[128*64];
    __shared__ unsigned short Bh2[64*64], Bl2[64*64];

    const int tid = threadIdx.x, lane = tid&63, wid = tid>>6;
    const int l15 = lane&15, l4 = lane>>4, l7 = lane&7;
    const int wr = wid>>1, wc = wid&1;

    int aSrc[4], bSrc[2];
#pragma unroll
    for (int s=0;s<4;++s){
        int idx = (wid + s*4)*64 + lane;
        int row = idx>>3, ch = idx&7;
        aSrc[s] = (row0+row)*E_ + ((ch ^ (row&7))<<3);
    }
#pragma unroll
    for (int s=0;s<2;++s){
        int idx = (wid + s*4)*64 + lane;
        int row = idx>>3, ch = idx&7;
        bSrc[s] = (col0+row)*E_ + ((ch ^ (row&7))<<3);
    }
    const int aBase = (wr*64 + l15)*128;
    const int bBase = (wc*32 + l15)*128;
    const int sw[2] = { ((l4^l7)<<4), ((((4+l4))^l7)<<4) };

    f32x4 acc[4][2];
    const f32x4 zero4 = {0.f,0.f,0.f,0.f};
#pragma unroll
    for (int m=0;m<4;++m)
#pragma unroll
        for (int n=0;n<2;++n) acc[m][n] = zero4;

    for (int kt=0;kt<12;++kt){
        const int k0 = kt*64;
        __syncthreads();
#pragma unroll
        for (int s=0;s<4;++s){
            gl16(Ah_g + aSrc[s] + k0, &Ah[(wid+s*4)*512]);
            gl16(Al_g + aSrc[s] + k0, &Al[(wid+s*4)*512]);
        }
#pragma unroll
        for (int s=0;s<2;++s){
            gl16(Wh + bSrc[s] + k0, &Bh2[(wid+s*4)*512]);
            gl16(Wl + bSrc[s] + k0, &Bl2[(wid+s*4)*512]);
        }
        __syncthreads();
#pragma unroll
        for (int kk=0;kk<2;++kk){
            bf16x8 ah[4], al[4], fbh[2], fbl[2];
#pragma unroll
            for (int m=0;m<4;++m){
                ah[m] = *(const bf16x8*)((const char*)Ah + aBase + m*2048 + sw[kk]);
                al[m] = *(const bf16x8*)((const char*)Al + aBase + m*2048 + sw[kk]);
            }
#pragma unroll
            for (int n=0;n<2;++n){
                fbh[n] = *(const bf16x8*)((const char*)Bh2 + bBase + n*2048 + sw[kk]);
                fbl[n] = *(const bf16x8*)((const char*)Bl2 + bBase + n*2048 + sw[kk]);
            }
#pragma unroll
            for (int m=0;m<4;++m)
#pragma unroll
                for (int n=0;n<2;++n){
                    acc[m][n] = MFMA16(ah[m], fbh[n], acc[m][n]);
                    acc[m][n] = MFMA16(ah[m], fbl[n], acc[m][n]);
                    acc[m][n] = MFMA16(al[m], fbh[n], acc[m][n]);
                }
        }
    }
#pragma unroll
    for (int m=0;m<4;++m)
#pragma unroll
        for (int n=0;n<2;++n){
            float bn = bias[col0 + wc*32 + n*16 + l15];
#pragma unroll
            for (int j=0;j<4;++j){
                int row = row0 + wr*64 + m*16 + l4*4 + j;
                int col = col0 + wc*32 + n*16 + l15;
                float I = acc[m][n][j] + bn;
                out[(long)row*E_ + col] = sigm(5.f*I - 10.f);   // lif_step(0, I) spike
            }
        }
}

// ---------------------------------------------------------------------------
extern "C" void kernel_launch(void* const* d_in, const int* in_sizes, int n_in,
                              void* d_out, int out_size, void* d_ws, size_t ws_size,
                              hipStream_t stream){
    const float* x  = (const float*)d_in[0];
    const float* Wq = (const float*)d_in[1];
    const float* bq = (const float*)d_in[2];
    const float* Wk = (const float*)d_in[3];
    const float* bk = (const float*)d_in[4];
    const float* Wv = (const float*)d_in[5];
    const float* bv = (const float*)d_in[6];
    const float* Wo = (const float*)d_in[7];
    const float* bo = (const float*)d_in[8];
    float* out = (float*)d_out;

    // ws layout (needs ~201 MiB):
    //  [0, 125829120)            enc bf16 [10][N][E]   (dead after qkv_k; att reuses)
    //  [125829120, 135266304)    whi/wlo bf16 [4][E*E] each 4.5MiB
    //  [135266304, 210763776)    Qf/Kf/Vf fp32 [N][E] each
    char* ws = (char*)d_ws;
    unsigned short* enc  = (unsigned short*)ws;
    unsigned short* atth = (unsigned short*)ws;
    unsigned short* attl = (unsigned short*)(ws + (long)NE_*2);
    unsigned short* whi  = (unsigned short*)(ws + 125829120L);
    unsigned short* wlo  = whi + 4L*WE_;
    float* Qf = (float*)(ws + 135266304L);
    float* Kf = Qf + NE_;
    float* Vf = Kf + NE_;

    wsplit_k<<<dim3(4*(WE_/8)/256), 256, 0, stream>>>(Wq,Wk,Wv,Wo,whi,wlo);
    encode_k<<<dim3(NE_/8/256), 256, 0, stream>>>(x,enc);
    qkv_k<<<dim3(64,12,3), 256, 0, stream>>>(enc,whi,wlo,bq,bk,bv,Qf,Kf,Vf);
    attn_k2<<<dim3(16,12,8), 256, 0, stream>>>(Qf,Kf,Vf,atth,attl);
    out_k<<<dim3(64,12), 256, 0, stream>>>(atth,attl,whi+3L*WE_,wlo+3L*WE_,bo,out);
}

// Round 3
// 685.360 us; speedup vs baseline: 6.8287x; 1.1685x over previous
//
#include <hip/hip_runtime.h>
#include <math.h>

// SpikingSelfAttention: B=8 S=1024 E=768 H=12 D=64 T=10
constexpr int B_ = 8, S_ = 1024, E_ = 768, H_ = 12, D_ = 64, T_ = 10;
constexpr int N_ = B_ * S_;        // 8192
constexpr int NE_ = N_ * E_;       // 6291456
constexpr int WE_ = E_ * E_;       // 589824

typedef __attribute__((ext_vector_type(8))) short bf16x8;
typedef __attribute__((ext_vector_type(4))) float f32x4;

#define MFMA16(a,b,c) __builtin_amdgcn_mfma_f32_16x16x32_bf16(a,b,c,0,0,0)

__device__ __forceinline__ float sigm(float z){ return 1.f/(1.f+__expf(-z)); }
__device__ __forceinline__ unsigned short f2bf(float f){
    unsigned int u = __float_as_uint(f);
    u += 0x7FFFu + ((u>>16)&1u);           // RN-even
    return (unsigned short)(u>>16);
}
__device__ __forceinline__ float bf2f(unsigned short h){
    return __uint_as_float(((unsigned int)h)<<16);
}
__device__ __forceinline__ void gl16(const void* g, void* l){
    __builtin_amdgcn_global_load_lds((const __attribute__((address_space(1))) unsigned int*)g,
                                     (__attribute__((address_space(3))) unsigned int*)l, 16, 0, 0);
}

// ---------------------------------------------------------------------------
// encode: enc[t][n][e] = bf16(sigmoid(100*clip(x,0,1) - 10t)), 8 elems/thread
__global__ __launch_bounds__(256) void encode_k(const float* __restrict__ x,
                                                unsigned short* __restrict__ enc){
    const int i = blockIdx.x*256 + threadIdx.x;
    const float4 a = ((const float4*)x)[2*i];
    const float4 b = ((const float4*)x)[2*i+1];
    float p[8] = {a.x,a.y,a.z,a.w,b.x,b.y,b.z,b.w};
#pragma unroll
    for (int e=0;e<8;++e) p[e] = 100.f*fminf(fmaxf(p[e],0.f),1.f);
#pragma unroll
    for (int t=0;t<T_;++t){
        unsigned int w[4];
#pragma unroll
        for (int e=0;e<4;++e){
            unsigned short u0 = f2bf(sigm(p[2*e]   - 10.f*(float)t));
            unsigned short u1 = f2bf(sigm(p[2*e+1] - 10.f*(float)t));
            w[e] = (unsigned int)u0 | ((unsigned int)u1<<16);
        }
        ((uint4*)(enc + (long)t*NE_))[i] = make_uint4(w[0],w[1],w[2],w[3]);
    }
}

// ---------------------------------------------------------------------------
// split weights into hi/lo bf16: whi[z], wlo[z], z in {q,k,v,o}
__global__ __launch_bounds__(256) void wsplit_k(const float* __restrict__ Wq, const float* __restrict__ Wk,
        const float* __restrict__ Wv, const float* __restrict__ Wo,
        unsigned short* __restrict__ whi, unsigned short* __restrict__ wlo){
    int gi = blockIdx.x*256 + threadIdx.x;
    int z = gi / (WE_/8);
    int r = gi % (WE_/8);
    const float* W = z==0?Wq : z==1?Wk : z==2?Wv : Wo;
    const float4 a = ((const float4*)W)[2*r];
    const float4 b = ((const float4*)W)[2*r+1];
    float f[8]={a.x,a.y,a.z,a.w,b.x,b.y,b.z,b.w};
    unsigned int h[4], l[4];
#pragma unroll
    for (int e=0;e<4;++e){
        unsigned short h0=f2bf(f[2*e]),   l0=f2bf(f[2*e]  -bf2f(h0));
        unsigned short h1=f2bf(f[2*e+1]), l1=f2bf(f[2*e+1]-bf2f(h1));
        h[e] = (unsigned)h0 | ((unsigned)h1<<16);
        l[e] = (unsigned)l0 | ((unsigned)l1<<16);
    }
    ((uint4*)(whi + (long)z*WE_))[r] = make_uint4(h[0],h[1],h[2],h[3]);
    ((uint4*)(wlo + (long)z*WE_))[r] = make_uint4(l[0],l[1],l[2],l[3]);
}

// ---------------------------------------------------------------------------
// fused QKV GEMM (MFMA, W plain bf16) + in-register LIF over 10 timesteps.
// tile 128x64, 4 waves (2x2). 3-slot LDS pipeline, counted vmcnt (T3/T4),
// raw s_barrier (no vmcnt(0) drain in main loop), setprio around MFMA (T5).
__global__ __launch_bounds__(256,2) void qkv_k(const unsigned short* __restrict__ enc,
        const unsigned short* __restrict__ whi,
        const float* __restrict__ bq, const float* __restrict__ bk, const float* __restrict__ bv,
        float* __restrict__ Qf, float* __restrict__ Kf, float* __restrict__ Vf){
    const int z = blockIdx.z;
    const unsigned short* Wh = whi + (long)z*WE_;
    const float* bias = z==0?bq : z==1?bk : bv;
    float* Out = z==0?Qf : z==1?Kf : Vf;
    const int row0 = blockIdx.x*128, col0 = blockIdx.y*64;

    __shared__ unsigned short Ab[3][128*64];   // 3 x 16KB
    __shared__ unsigned short Bh[3][64*64];    // 3 x 8KB

    const int tid = threadIdx.x, lane = tid&63, wid = tid>>6;
    const int l15 = lane&15, l4 = lane>>4, l7 = lane&7;
    const int wr = wid>>1, wc = wid&1;

    // staging source offsets (element units); LDS dest linear, source pre-inverse-swizzled
    int aSrc[4], bSrc[2];
#pragma unroll
    for (int s=0;s<4;++s){
        int idx = (wid + s*4)*64 + lane;      // [0,1024)
        int row = idx>>3, ch = idx&7;
        aSrc[s] = (row0+row)*E_ + ((ch ^ (row&7))<<3);
    }
#pragma unroll
    for (int s=0;s<2;++s){
        int idx = (wid + s*4)*64 + lane;      // [0,512)
        int row = idx>>3, ch = idx&7;
        bSrc[s] = (col0+row)*E_ + ((ch ^ (row&7))<<3);
    }

    const int aBase = (wr*64 + l15)*128;
    const int bBase = (wc*32 + l15)*128;
    const int sw[2] = { ((l4^l7)<<4), ((((4+l4))^l7)<<4) };

    f32x4 acc[4][2];
    float vm[4][2][4] = {};     // membrane potential (registers across t)
    float qa[4][2][4] = {};     // spike accumulator
    float bn[2];
#pragma unroll
    for (int n=0;n<2;++n) bn[n] = bias[col0 + wc*32 + n*16 + l15];
    // force the bias loads to complete BEFORE the pipeline starts, so the
    // backend doesn't insert a vmcnt wait mid-pipeline for them.
    asm volatile("" :: "v"(bn[0]), "v"(bn[1]));

    const f32x4 zero4 = {0.f,0.f,0.f,0.f};

#define STAGE(tt, kk2, slot)                                               \
    do {                                                                   \
        const unsigned short* eb_ = enc + (long)(tt)*NE_ + (kk2)*64;       \
        _Pragma("unroll")                                                  \
        for (int s_=0;s_<4;++s_)                                           \
            gl16(eb_ + aSrc[s_], &Ab[slot][(wid+s_*4)*512]);               \
        _Pragma("unroll")                                                  \
        for (int s_=0;s_<2;++s_)                                           \
            gl16(Wh + bSrc[s_] + (kk2)*64, &Bh[slot][(wid+s_*4)*512]);     \
    } while(0)

    // prologue: stage steps 0 and 1
    STAGE(0, 0, 0);
    STAGE(0, 1, 1);

    for (int t=0;t<T_;++t){
#pragma unroll
        for (int m=0;m<4;++m)
#pragma unroll
            for (int n=0;n<2;++n) acc[m][n] = zero4;
#pragma unroll
        for (int kt=0;kt<12;++kt){
            const int slotC = kt%3;            // compute slot (compile-time)
            const int slotS = (kt+2)%3;        // stage slot   (compile-time)
            if (kt < 10){
                STAGE(t, kt+2, slotS);
                asm volatile("s_waitcnt vmcnt(12)" ::: "memory");
            } else if (t < 9){
                STAGE(t+1, kt-10, slotS);
                asm volatile("s_waitcnt vmcnt(12)" ::: "memory");
            } else if (kt == 10){
                asm volatile("s_waitcnt vmcnt(6)" ::: "memory");
            } else {
                asm volatile("s_waitcnt vmcnt(0)" ::: "memory");
            }
            __builtin_amdgcn_s_barrier();      // all waves' loads for this slot done
            __builtin_amdgcn_s_setprio(1);
#pragma unroll
            for (int kk=0;kk<2;++kk){
                bf16x8 af[4], fbh[2];
#pragma unroll
                for (int m=0;m<4;++m)
                    af[m] = *(const bf16x8*)((const char*)&Ab[slotC][0] + aBase + m*2048 + sw[kk]);
#pragma unroll
                for (int n=0;n<2;++n)
                    fbh[n] = *(const bf16x8*)((const char*)&Bh[slotC][0] + bBase + n*2048 + sw[kk]);
#pragma unroll
                for (int m=0;m<4;++m)
#pragma unroll
                    for (int n=0;n<2;++n)
                        acc[m][n] = MFMA16(af[m], fbh[n], acc[m][n]);
            }
            __builtin_amdgcn_s_setprio(0);
            __builtin_amdgcn_s_barrier();      // LDS reads done before slot reuse
        }
        // LIF update, registers only (no barrier needed; prefetch stays in flight)
#pragma unroll
        for (int m=0;m<4;++m)
#pragma unroll
            for (int n=0;n<2;++n)
#pragma unroll
                for (int j=0;j<4;++j){
                    float I = acc[m][n][j] + bn[n];
                    float v = (vm[m][n][j] + I)*0.5f;
                    float s = sigm(10.f*v - 10.f);
                    vm[m][n][j] = v*(1.f - s);
                    qa[m][n][j] += s;
                }
    }
#undef STAGE
#pragma unroll
    for (int m=0;m<4;++m)
#pragma unroll
        for (int n=0;n<2;++n)
#pragma unroll
            for (int j=0;j<4;++j){
                int row = row0 + wr*64 + m*16 + l4*4 + j;
                int col = col0 + wc*32 + n*16 + l15;
                Out[(long)row*E_ + col] = qa[m][n][j];
            }
}

// ---------------------------------------------------------------------------
// flash attention, hi/lo-split bf16 MFMA. Per block: 64 q-rows, one (b,h).
// S^T = mfma(K, Q^T-frags); softmax per-lane q; O^T = mfma(V^T, P^T).
__global__ __launch_bounds__(256,2) void attn_k2(const float* __restrict__ Qf, const float* __restrict__ Kf,
        const float* __restrict__ Vf, unsigned short* __restrict__ atth, unsigned short* __restrict__ attl){
    const int q0 = blockIdx.x*64;
    const int h  = blockIdx.y;
    const int b  = blockIdx.z;
    const long base = ((long)b*S_)*E_ + h*64;

    __shared__ char smem[65536];
    unsigned short* Qh = (unsigned short*)(smem);
    unsigned short* Ql = (unsigned short*)(smem + 8192);
    unsigned short* Kh = (unsigned short*)(smem + 16384);
    unsigned short* Kl = (unsigned short*)(smem + 24576);
    unsigned short* Vh = (unsigned short*)(smem + 32768);  // [d][key] transposed
    unsigned short* Vl = (unsigned short*)(smem + 40960);
    unsigned short* Ph = (unsigned short*)(smem + 49152);  // [q][key]
    unsigned short* Pl = (unsigned short*)(smem + 57344);
    float* OT = (float*)(smem + 16384);                    // [64][68] reuse K/V region

    const int tid = threadIdx.x, lane = tid&63, wid = tid>>6;
    const int l15 = lane&15, l4 = lane>>4, l7 = lane&7;
    const int qrow = wid*16 + l15;

    // stage Q split (once)
    {
        int q = tid>>2, c0 = (tid&3)*2;
        const float* src = Qf + base + (long)(q0+q)*E_ + (tid&3)*16;
        float4 f0=((const float4*)src)[0], f1=((const float4*)src)[1];
        float4 f2=((const float4*)src)[2], f3=((const float4*)src)[3];
        float f[16]={f0.x,f0.y,f0.z,f0.w,f1.x,f1.y,f1.z,f1.w,f2.x,f2.y,f2.z,f2.w,f3.x,f3.y,f3.z,f3.w};
        bf16x8 vh[2], vl[2];
#pragma unroll
        for (int g=0;g<2;++g)
#pragma unroll
            for (int e=0;e<8;++e){
                unsigned short hh = f2bf(f[g*8+e]);
                vh[g][e] = (short)hh;
                vl[g][e] = (short)f2bf(f[g*8+e]-bf2f(hh));
            }
        int by0 = q*128 + (((c0  ) ^ (q&7))<<4);
        int by1 = q*128 + (((c0+1) ^ (q&7))<<4);
        *(bf16x8*)((char*)Qh + by0) = vh[0];
        *(bf16x8*)((char*)Qh + by1) = vh[1];
        *(bf16x8*)((char*)Ql + by0) = vl[0];
        *(bf16x8*)((char*)Ql + by1) = vl[1];
    }
    __syncthreads();
    bf16x8 qfh[2], qfl[2];
#pragma unroll
    for (int kk=0;kk<2;++kk){
        int off = qrow*128 + ((((kk<<2)+l4) ^ l7)<<4);
        qfh[kk] = *(const bf16x8*)((const char*)Qh + off);
        qfl[kk] = *(const bf16x8*)((const char*)Ql + off);
    }

    float mrun = -1e30f, lrun = 0.f;
    f32x4 ot[4];
    const f32x4 zero4 = {0.f,0.f,0.f,0.f};
#pragma unroll
    for (int m=0;m<4;++m) ot[m] = zero4;

    for (int kt=0;kt<16;++kt){
        const int k0 = kt*64;
        __syncthreads();
        // stage K split
        {
            int key = tid>>2, c0 = (tid&3)*2;
            const float* src = Kf + base + (long)(k0+key)*E_ + (tid&3)*16;
            float4 f0=((const float4*)src)[0], f1=((const float4*)src)[1];
            float4 f2=((const float4*)src)[2], f3=((const float4*)src)[3];
            float f[16]={f0.x,f0.y,f0.z,f0.w,f1.x,f1.y,f1.z,f1.w,f2.x,f2.y,f2.z,f2.w,f3.x,f3.y,f3.z,f3.w};
            bf16x8 vh[2], vl[2];
#pragma unroll
            for (int g=0;g<2;++g)
#pragma unroll
                for (int e=0;e<8;++e){
                    unsigned short hh = f2bf(f[g*8+e]);
                    vh[g][e] = (short)hh;
                    vl[g][e] = (short)f2bf(f[g*8+e]-bf2f(hh));
                }
            int by0 = key*128 + (((c0  ) ^ (key&7))<<4);
            int by1 = key*128 + (((c0+1) ^ (key&7))<<4);
            *(bf16x8*)((char*)Kh + by0) = vh[0];
            *(bf16x8*)((char*)Kh + by1) = vh[1];
            *(bf16x8*)((char*)Kl + by0) = vl[0];
            *(bf16x8*)((char*)Kl + by1) = vl[1];
        }
        // stage V transposed + split, packed b32 writes
#pragma unroll
        for (int rr=0;rr<2;++rr){
            int dq = (tid>>5) + rr*8;      // d-quad [0,16)
            int kp = tid&31;               // key pair
            const float* s0 = Vf + base + (long)(k0 + 2*kp)*E_ + dq*4;
            float4 va = *(const float4*)s0;
            float4 vb = *(const float4*)(s0 + E_);
            float fa[4]={va.x,va.y,va.z,va.w}, fb[4]={vb.x,vb.y,vb.z,vb.w};
#pragma unroll
            for (int dd=0;dd<4;++dd){
                int d = dq*4+dd;
                unsigned short ha=f2bf(fa[dd]), hb=f2bf(fb[dd]);
                unsigned short la=f2bf(fa[dd]-bf2f(ha)), lb=f2bf(fb[dd]-bf2f(hb));
                int byte = d*128 + ((kp<<2) ^ ((d&7)<<4));
                *(unsigned int*)((char*)Vh + byte) = (unsigned)ha | ((unsigned)hb<<16);
                *(unsigned int*)((char*)Vl + byte) = (unsigned)la | ((unsigned)lb<<16);
            }
        }
        __syncthreads();
        // S^T = K * Q^T  (3 hi/lo products)
        f32x4 st[4];
#pragma unroll
        for (int m=0;m<4;++m) st[m] = zero4;
#pragma unroll
        for (int kk=0;kk<2;++kk){
            int swo = ((((kk<<2)+l4) ^ l7)<<4);
            bf16x8 kh[4], kl2[4];
#pragma unroll
            for (int m=0;m<4;++m){
                int off = (m*16+l15)*128 + swo;
                kh[m]  = *(const bf16x8*)((const char*)Kh + off);
                kl2[m] = *(const bf16x8*)((const char*)Kl + off);
            }
#pragma unroll
            for (int m=0;m<4;++m){
                st[m] = MFMA16(kh[m],  qfh[kk], st[m]);
                st[m] = MFMA16(kh[m],  qfl[kk], st[m]);
                st[m] = MFMA16(kl2[m], qfh[kk], st[m]);
            }
        }
        // online softmax (lane's q = qrow; 4 lanes share a q via xor16/32)
        float pmax = -1e30f;
#pragma unroll
        for (int m=0;m<4;++m)
#pragma unroll
            for (int j=0;j<4;++j){ st[m][j] *= 0.125f; pmax = fmaxf(pmax, st[m][j]); }
        pmax = fmaxf(pmax, __shfl_xor(pmax,16));
        pmax = fmaxf(pmax, __shfl_xor(pmax,32));
        float mnew = fmaxf(mrun, pmax);
        float alpha = __expf(mrun - mnew);
        float p[16]; float psum = 0.f;
#pragma unroll
        for (int m=0;m<4;++m)
#pragma unroll
            for (int j=0;j<4;++j){ float e = __expf(st[m][j]-mnew); p[m*4+j]=e; psum+=e; }
        psum += __shfl_xor(psum,16);
        psum += __shfl_xor(psum,32);
        lrun = lrun*alpha + psum;
        mrun = mnew;
#pragma unroll
        for (int m=0;m<4;++m)
#pragma unroll
            for (int j=0;j<4;++j) ot[m][j] *= alpha;
        // write P^T split (wave-private rows, packed pairs)
#pragma unroll
        for (int m=0;m<4;++m)
#pragma unroll
            for (int jp=0;jp<2;++jp){
                float fx = p[m*4+jp*2], fy = p[m*4+jp*2+1];
                unsigned short hx=f2bf(fx), hy=f2bf(fy);
                unsigned short lx=f2bf(fx-bf2f(hx)), ly=f2bf(fy-bf2f(hy));
                int key = m*16 + l4*4 + jp*2;
                int byte = qrow*128 + ((key<<1) ^ (l7<<4));
                *(unsigned int*)((char*)Ph + byte) = (unsigned)hx | ((unsigned)hy<<16);
                *(unsigned int*)((char*)Pl + byte) = (unsigned)lx | ((unsigned)ly<<16);
            }
        // O^T += V^T * P^T (3 hi/lo products)
#pragma unroll
        for (int kk=0;kk<2;++kk){
            int swo = ((((kk<<2)+l4) ^ l7)<<4);
            bf16x8 pfh = *(const bf16x8*)((const char*)Ph + qrow*128 + swo);
            bf16x8 pfl = *(const bf16x8*)((const char*)Pl + qrow*128 + swo);
#pragma unroll
            for (int m=0;m<4;++m){
                int off = (m*16+l15)*128 + swo;
                bf16x8 vvh = *(const bf16x8*)((const char*)Vh + off);
                bf16x8 vvl = *(const bf16x8*)((const char*)Vl + off);
                ot[m] = MFMA16(vvh, pfh, ot[m]);
                ot[m] = MFMA16(vvh, pfl, ot[m]);
                ot[m] = MFMA16(vvl, pfh, ot[m]);
            }
        }
    }
    __syncthreads();
    // normalize + transpose via LDS, write att split bf16
    float inv = 1.f/lrun;
#pragma unroll
    for (int m=0;m<4;++m)
#pragma unroll
        for (int j=0;j<4;++j){
            int d = m*16 + l4*4 + j;
            OT[qrow*68 + d] = ot[m][j]*inv;
        }
    __syncthreads();
    {
        int q = tid>>2, d0 = (tid&3)*16;
        const float* rp = OT + q*68 + d0;
        float4 f0=((const float4*)rp)[0], f1=((const float4*)rp)[1];
        float4 f2=((const float4*)rp)[2], f3=((const float4*)rp)[3];
        float f[16]={f0.x,f0.y,f0.z,f0.w,f1.x,f1.y,f1.z,f1.w,f2.x,f2.y,f2.z,f2.w,f3.x,f3.y,f3.z,f3.w};
        bf16x8 vh[2], vl[2];
#pragma unroll
        for (int g=0;g<2;++g)
#pragma unroll
            for (int e=0;e<8;++e){
                unsigned short hh = f2bf(f[g*8+e]);
                vh[g][e] = (short)hh;
                vl[g][e] = (short)f2bf(f[g*8+e]-bf2f(hh));
            }
        long o = base + (long)(q0+q)*E_ + d0;
        *(bf16x8*)(atth + o)     = vh[0];
        *(bf16x8*)(atth + o + 8) = vh[1];
        *(bf16x8*)(attl + o)     = vl[0];
        *(bf16x8*)(attl + o + 8) = vl[1];
    }
}

// ---------------------------------------------------------------------------
// output projection GEMM (att hi/lo x Wo hi/lo, 3 products) + fresh-state spike
__global__ __launch_bounds__(256,2) void out_k(const unsigned short* __restrict__ Ah_g,
        const unsigned short* __restrict__ Al_g,
        const unsigned short* __restrict__ Wh, const unsigned short* __restrict__ Wl,
        const float* __restrict__ bias, float* __restrict__ out){
    const int row0 = blockIdx.x*128, col0 = blockIdx.y*64;
    __shared__ unsigned short Ah[128*64], Al[128*64];
    __shared__ unsigned short Bh2[64*64], Bl2[64*64];

    const int tid = threadIdx.x, lane = tid&63, wid = tid>>6;
    const int l15 = lane&15, l4 = lane>>4, l7 = lane&7;
    const int wr = wid>>1, wc = wid&1;

    int aSrc[4], bSrc[2];
#pragma unroll
    for (int s=0;s<4;++s){
        int idx = (wid + s*4)*64 + lane;
        int row = idx>>3, ch = idx&7;
        aSrc[s] = (row0+row)*E_ + ((ch ^ (row&7))<<3);
    }
#pragma unroll
    for (int s=0;s<2;++s){
        int idx = (wid + s*4)*64 + lane;
        int row = idx>>3, ch = idx&7;
        bSrc[s] = (col0+row)*E_ + ((ch ^ (row&7))<<3);
    }
    const int aBase = (wr*64 + l15)*128;
    const int bBase = (wc*32 + l15)*128;
    const int sw[2] = { ((l4^l7)<<4), ((((4+l4))^l7)<<4) };

    f32x4 acc[4][2];
    const f32x4 zero4 = {0.f,0.f,0.f,0.f};
#pragma unroll
    for (int m=0;m<4;++m)
#pragma unroll
        for (int n=0;n<2;++n) acc[m][n] = zero4;

    for (int kt=0;kt<12;++kt){
        const int k0 = kt*64;
        __syncthreads();
#pragma unroll
        for (int s=0;s<4;++s){
            gl16(Ah_g + aSrc[s] + k0, &Ah[(wid+s*4)*512]);
            gl16(Al_g + aSrc[s] + k0, &Al[(wid+s*4)*512]);
        }
#pragma unroll
        for (int s=0;s<2;++s){
            gl16(Wh + bSrc[s] + k0, &Bh2[(wid+s*4)*512]);
            gl16(Wl + bSrc[s] + k0, &Bl2[(wid+s*4)*512]);
        }
        __syncthreads();
#pragma unroll
        for (int kk=0;kk<2;++kk){
            bf16x8 ah[4], al[4], fbh[2], fbl[2];
#pragma unroll
            for (int m=0;m<4;++m){
                ah[m] = *(const bf16x8*)((const char*)Ah + aBase + m*2048 + sw[kk]);
                al[m] = *(const bf16x8*)((const char*)Al + aBase + m*2048 + sw[kk]);
            }
#pragma unroll
            for (int n=0;n<2;++n){
                fbh[n] = *(const bf16x8*)((const char*)Bh2 + bBase + n*2048 + sw[kk]);
                fbl[n] = *(const bf16x8*)((const char*)Bl2 + bBase + n*2048 + sw[kk]);
            }
#pragma unroll
            for (int m=0;m<4;++m)
#pragma unroll
                for (int n=0;n<2;++n){
                    acc[m][n] = MFMA16(ah[m], fbh[n], acc[m][n]);
                    acc[m][n] = MFMA16(ah[m], fbl[n], acc[m][n]);
                    acc[m][n] = MFMA16(al[m], fbh[n], acc[m][n]);
                }
        }
    }
#pragma unroll
    for (int m=0;m<4;++m)
#pragma unroll
        for (int n=0;n<2;++n){
            float bn = bias[col0 + wc*32 + n*16 + l15];
#pragma unroll
            for (int j=0;j<4;++j){
                int row = row0 + wr*64 + m*16 + l4*4 + j;
                int col = col0 + wc*32 + n*16 + l15;
                float I = acc[m][n][j] + bn;
                out[(long)row*E_ + col] = sigm(5.f*I - 10.f);   // lif_step(0, I) spike
            }
        }
}

// ---------------------------------------------------------------------------
extern "C" void kernel_launch(void* const* d_in, const int* in_sizes, int n_in,
                              void* d_out, int out_size, void* d_ws, size_t ws_size,
                              hipStream_t stream){
    const float* x  = (const float*)d_in[0];
    const float* Wq = (const float*)d_in[1];
    const float* bq = (const float*)d_in[2];
    const float* Wk = (const float*)d_in[3];
    const float* bk = (const float*)d_in[4];
    const float* Wv = (const float*)d_in[5];
    const float* bv = (const float*)d_in[6];
    const float* Wo = (const float*)d_in[7];
    const float* bo = (const float*)d_in[8];
    float* out = (float*)d_out;

    // ws layout (~201 MiB):
    //  [0, 125829120)            enc bf16 [10][N][E]   (dead after qkv_k; att reuses)
    //  [125829120, 135266304)    whi/wlo bf16 [4][E*E]
    //  [135266304, 210763776)    Qf/Kf/Vf fp32 [N][E]
    char* ws = (char*)d_ws;
    unsigned short* enc  = (unsigned short*)ws;
    unsigned short* atth = (unsigned short*)ws;
    unsigned short* attl = (unsigned short*)(ws + (long)NE_*2);
    unsigned short* whi  = (unsigned short*)(ws + 125829120L);
    unsigned short* wlo  = whi + 4L*WE_;
    float* Qf = (float*)(ws + 135266304L);
    float* Kf = Qf + NE_;
    float* Vf = Kf + NE_;

    wsplit_k<<<dim3(4*(WE_/8)/256), 256, 0, stream>>>(Wq,Wk,Wv,Wo,whi,wlo);
    encode_k<<<dim3(NE_/8/256), 256, 0, stream>>>(x,enc);
    qkv_k<<<dim3(64,12,3), 256, 0, stream>>>(enc,whi,bq,bk,bv,Qf,Kf,Vf);
    attn_k2<<<dim3(16,12,8), 256, 0, stream>>>(Qf,Kf,Vf,atth,attl);
    out_k<<<dim3(64,12), 256, 0, stream>>>(atth,attl,whi+3L*WE_,wlo+3L*WE_,bo,out);
}